// Round 9
// baseline (375.034 us; speedup 1.0000x reference)
//
#include <hip/hip_runtime.h>
#include <math.h>

#define NTOK   16384
#define DIM    2048
#define NEXP   64
#define TOPK   8
#define TB     16          // tokens per block (1 token-tile)
#define KC     64          // K chunk
#define NCHUNK (DIM / KC)  // 32

typedef double v4d __attribute__((ext_vector_type(4)));

// ---- single fused kernel: 4 waves x 4 k-split MFMA chains, global->reg direct ----
__global__ __launch_bounds__(256, 4) void router_kernel(
    const float* __restrict__ x, const float* __restrict__ proto,
    float* __restrict__ out)
{
    __shared__ float  logits[TB][NEXP];   // 4 KiB
    __shared__ double xinv_lds[TB];
    __shared__ double pinv_lds[NEXP];

    const int tid  = threadIdx.x;
    const int lane = tid & 63;
    const int w    = tid >> 6;            // wave 0..3 = expert tile
    const int tok0 = blockIdx.x * TB;

    const int etile = w;                  // wave owns experts [16w, 16w+16)
    const int arow  = lane & 15;          // A-row / B-col label
    const int akg   = lane >> 4;          // quarter-wave k-group
    const int kbase = akg * 16;           // lane's private 16-k segment

    // ---- layout calibration (verified r4): (lane,reg) -> (row,col) ----
    v4d c1 = {0., 0., 0., 0.}, c2 = {0., 0., 0., 0.};
    c1 = __builtin_amdgcn_mfma_f64_16x16x4f64((double)arow, 1.0, c1, 0, 0, 0);
    c2 = __builtin_amdgcn_mfma_f64_16x16x4f64(1.0, (double)arow, c2, 0, 0, 0);

    // 4 independent k-split chains for the wave's single output tile
    v4d acc0 = {0., 0., 0., 0.}, acc1 = {0., 0., 0., 0.};
    v4d acc2 = {0., 0., 0., 0.}, acc3 = {0., 0., 0., 0.};
    double sumsq = 0.0, psq = 0.0;

    const float* xrow = x     + (size_t)(tok0 + arow)       * DIM + kbase;
    const float* prow = proto + (size_t)(etile * 16 + arow) * DIM + kbase;

    float4 axp[4], bxp[4];   // buffer X (even chunks)
    float4 ayp[4], byp[4];   // buffer Y (odd chunks)

#define LOADSET(A, B, c) do {                                       \
    const int _off = (c) * KC;                                      \
    _Pragma("unroll")                                               \
    for (int q = 0; q < 4; ++q) {                                   \
        A[q] = *(const float4*)(xrow + _off + 4 * q);               \
        B[q] = *(const float4*)(prow + _off + 4 * q);               \
    } } while (0)

// chain j consumes float4 slot q=j; round-robin over chains per scalar s
#define CHAIN_STEP(A, B, S)                                                        \
    acc0 = __builtin_amdgcn_mfma_f64_16x16x4f64((double)A[0].S, (double)B[0].S, acc0, 0, 0, 0); \
    acc1 = __builtin_amdgcn_mfma_f64_16x16x4f64((double)A[1].S, (double)B[1].S, acc1, 0, 0, 0); \
    acc2 = __builtin_amdgcn_mfma_f64_16x16x4f64((double)A[2].S, (double)B[2].S, acc2, 0, 0, 0); \
    acc3 = __builtin_amdgcn_mfma_f64_16x16x4f64((double)A[3].S, (double)B[3].S, acc3, 0, 0, 0);

#define COMPUTE(A, B) do {                                          \
    _Pragma("unroll")                                               \
    for (int q = 0; q < 4; ++q) {   /* norms, r8 statement order */ \
        double a0 = (double)A[q].x, a1 = (double)A[q].y,            \
               a2 = (double)A[q].z, a3 = (double)A[q].w;            \
        double u0 = (double)B[q].x, u1 = (double)B[q].y,            \
               u2 = (double)B[q].z, u3 = (double)B[q].w;            \
        sumsq += a0*a0 + a1*a1 + a2*a2 + a3*a3;                     \
        psq   += u0*u0 + u1*u1 + u2*u2 + u3*u3;                     \
    }                                                               \
    CHAIN_STEP(A, B, x)                                             \
    CHAIN_STEP(A, B, y)                                             \
    CHAIN_STEP(A, B, z)                                             \
    CHAIN_STEP(A, B, w)                                             \
    } while (0)

    // ---- barrier-free main loop, unroll-by-2 with named buffers ----
    LOADSET(axp, bxp, 0);
    for (int c = 0; c < NCHUNK; c += 2) {
        LOADSET(ayp, byp, c + 1);              // prefetch odd chunk
        COMPUTE(axp, bxp);                     // compute even chunk
        if (c + 2 < NCHUNK) LOADSET(axp, bxp, c + 2);
        COMPUTE(ayp, byp);                     // compute odd chunk
    }

    // ---- combine k-split chains (f64 adds; ~1e-16 rel order change) ----
    const v4d acc = (acc0 + acc1) + (acc2 + acc3);

    // ---- norms: butterfly over the 4 k-quarters (r8 pattern) ----
    sumsq += __shfl_xor(sumsq, 16, 64);
    sumsq += __shfl_xor(sumsq, 32, 64);
    psq   += __shfl_xor(psq, 16, 64);
    psq   += __shfl_xor(psq, 32, 64);
    if (akg == 0) {   // all waves write identical xinv bits -> benign
        xinv_lds[arow]              = 1.0 / fmax(sqrt(sumsq), 1e-12);
        pinv_lds[etile * 16 + arow] = 1.0 / fmax(sqrt(psq), 1e-12);
    }
    __syncthreads();

    // ---- scale to cosine logits via calibrated labels, cast fp32, reshard ----
#pragma unroll
    for (int i = 0; i < 4; ++i) {
        const int tr = (int)(c1[i] * 0.25);      // true token-within-tile label
        const int ec = (int)(c2[i] * 0.25);      // true expert-within-16 label
        const int e  = etile * 16 + ec;
        logits[tr][e] = (float)(acc[i] * xinv_lds[tr] * pinv_lds[e]);
    }
    __syncthreads();

    // ---- epilogue: np fp32 softmax bit-chain + rank by (w32 desc, idx asc) ----
#pragma unroll 1
    for (int i = 0; i < 4; ++i) {
        const int tl = w * 4 + i;
        const float l32 = logits[tl][lane];

        float m = l32;
#pragma unroll
        for (int d = 1; d < 64; d <<= 1) {
            float o = __shfl_xor(m, d, 64);
            m = fmaxf(m, o);
        }
        const float dd = l32 - m;
        const float e32 = (float)exp((double)dd);

        // numpy pairwise_sum (n=64): 8 accumulators over stride 8
        float r[8];
#pragma unroll
        for (int j = 0; j < 8; ++j) {
            float rj = __shfl(e32, j, 64);
#pragma unroll
            for (int b = 1; b < 8; ++b)
                rj += __shfl(e32, j + 8 * b, 64);
            r[j] = rj;
        }
        const float S = ((r[0] + r[1]) + (r[2] + r[3])) +
                        ((r[4] + r[5]) + (r[6] + r[7]));
        const float wgt = e32 / S;

        int rank = 0;
#pragma unroll 1
        for (int sdist = 1; sdist < 64; ++sdist) {
            float ow = __shfl_xor(wgt, sdist, 64);
            int j = lane ^ sdist;
            rank += (ow > wgt) || (ow == wgt && j < lane);
        }

        if (rank < TOPK) {
            const int tok = tok0 + tl;
            out[tok * TOPK + rank] = wgt;                       // routing_weights
            out[NTOK * TOPK + tok * TOPK + rank] = (float)lane; // selected_experts
        }
    }
}

extern "C" void kernel_launch(void* const* d_in, const int* in_sizes, int n_in,
                              void* d_out, int out_size, void* d_ws, size_t ws_size,
                              hipStream_t stream) {
    const float* x     = (const float*)d_in[0];
    const float* proto = (const float*)d_in[1];
    float* out         = (float*)d_out;
    (void)d_ws; (void)ws_size; (void)in_sizes; (void)n_in; (void)out_size;

    router_kernel<<<NTOK / TB, 256, 0, stream>>>(x, proto, out);
}

// Round 10
// 232.311 us; speedup vs baseline: 1.6144x; 1.6144x over previous
//
#include <hip/hip_runtime.h>
#include <math.h>

#define NTOK   16384
#define DIM    2048
#define NEXP   64
#define TOPK   8
#define TB     16          // tokens per block -> grid 1024 = 4 blocks/CU
#define KC     64          // K chunk
#define NCHUNK (DIM / KC)  // 32

typedef double v4d __attribute__((ext_vector_type(4)));

// ---- fused kernel: 4 waves x 2 k-split MFMA chains, global->reg, no spills ----
__global__ __launch_bounds__(256, 4) void router_kernel(
    const float* __restrict__ x, const float* __restrict__ proto,
    float* __restrict__ out)
{
    __shared__ float  logits[TB][NEXP];   // 4 KiB
    __shared__ double xinv_lds[TB];
    __shared__ double pinv_lds[NEXP];

    const int tid  = threadIdx.x;
    const int lane = tid & 63;
    const int w    = tid >> 6;            // wave 0..3 = expert tile
    const int tok0 = blockIdx.x * TB;

    const int etile = w;                  // wave owns experts [16w, 16w+16)
    const int arow  = lane & 15;          // A-row / B-col label
    const int akg   = lane >> 4;          // quarter-wave k-group
    const int kbase = akg * 16;           // lane's private 16-k segment

    // 2 independent k-split chains (chain0: q=0,1 ; chain1: q=2,3)
    v4d acc0 = {0., 0., 0., 0.}, acc1 = {0., 0., 0., 0.};
    double sumsq = 0.0, psq = 0.0;

    const float* xrow = x     + (size_t)(tok0 + arow)       * DIM + kbase;
    const float* prow = proto + (size_t)(etile * 16 + arow) * DIM + kbase;

    // named operand buffers (no arrays -> no spill ambiguity)
    float4 xa0, xa1, xa2, xa3, pa0, pa1, pa2, pa3;   // set A (even chunks)
    float4 xb0, xb1, xb2, xb3, pb0, pb1, pb2, pb3;   // set B (odd chunks)

#define LOADSET(A0, A1, A2, A3, B0, B1, B2, B3, c) do {             \
    const float* _xp = xrow + (c) * KC;                             \
    const float* _pp = prow + (c) * KC;                             \
    A0 = *(const float4*)(_xp);      A1 = *(const float4*)(_xp + 4);\
    A2 = *(const float4*)(_xp + 8);  A3 = *(const float4*)(_xp + 12);\
    B0 = *(const float4*)(_pp);      B1 = *(const float4*)(_pp + 4);\
    B2 = *(const float4*)(_pp + 8);  B3 = *(const float4*)(_pp + 12);\
    } while (0)

#define NORMQ(A, B) do {                                            \
    double a0 = (double)A.x, a1 = (double)A.y,                      \
           a2 = (double)A.z, a3 = (double)A.w;                      \
    double u0 = (double)B.x, u1 = (double)B.y,                      \
           u2 = (double)B.z, u3 = (double)B.w;                      \
    sumsq += a0*a0 + a1*a1 + a2*a2 + a3*a3;                         \
    psq   += u0*u0 + u1*u1 + u2*u2 + u3*u3;                         \
    } while (0)

#define MFMA2(Aq, Bq, Ar, Br, S)                                                        \
    acc0 = __builtin_amdgcn_mfma_f64_16x16x4f64((double)Aq.S, (double)Bq.S, acc0, 0, 0, 0); \
    acc1 = __builtin_amdgcn_mfma_f64_16x16x4f64((double)Ar.S, (double)Br.S, acc1, 0, 0, 0);

#define COMPUTE(A0, A1, A2, A3, B0, B1, B2, B3) do {                \
    NORMQ(A0, B0); NORMQ(A1, B1); NORMQ(A2, B2); NORMQ(A3, B3);     \
    MFMA2(A0, B0, A2, B2, x)                                        \
    MFMA2(A0, B0, A2, B2, y)                                        \
    MFMA2(A0, B0, A2, B2, z)                                        \
    MFMA2(A0, B0, A2, B2, w)                                        \
    MFMA2(A1, B1, A3, B3, x)                                        \
    MFMA2(A1, B1, A3, B3, y)                                        \
    MFMA2(A1, B1, A3, B3, z)                                        \
    MFMA2(A1, B1, A3, B3, w)                                        \
    } while (0)

    // ---- barrier-free main loop, unroll-by-2, named double buffers ----
    LOADSET(xa0, xa1, xa2, xa3, pa0, pa1, pa2, pa3, 0);
    for (int c = 0; c < NCHUNK; c += 2) {
        LOADSET(xb0, xb1, xb2, xb3, pb0, pb1, pb2, pb3, c + 1);
        COMPUTE(xa0, xa1, xa2, xa3, pa0, pa1, pa2, pa3);
        if (c + 2 < NCHUNK)
            LOADSET(xa0, xa1, xa2, xa3, pa0, pa1, pa2, pa3, c + 2);
        COMPUTE(xb0, xb1, xb2, xb3, pb0, pb1, pb2, pb3);
    }

    // ---- combine k-split chains (f64; ~1e-16 rel order change, flip-safe) ----
    const v4d acc = acc0 + acc1;

    // ---- norms: butterfly over the 4 k-quarters (r8/r9 pattern) ----
    sumsq += __shfl_xor(sumsq, 16, 64);
    sumsq += __shfl_xor(sumsq, 32, 64);
    psq   += __shfl_xor(psq, 16, 64);
    psq   += __shfl_xor(psq, 32, 64);
    if (akg == 0) {   // duplicate waves write identical xinv bits -> benign
        xinv_lds[arow]              = 1.0 / fmax(sqrt(sumsq), 1e-12);
        pinv_lds[etile * 16 + arow] = 1.0 / fmax(sqrt(psq), 1e-12);
    }

    // ---- layout calibration (verified r4), AFTER loop to shrink live range ----
    v4d c1 = {0., 0., 0., 0.}, c2 = {0., 0., 0., 0.};
    c1 = __builtin_amdgcn_mfma_f64_16x16x4f64((double)arow, 1.0, c1, 0, 0, 0);
    c2 = __builtin_amdgcn_mfma_f64_16x16x4f64(1.0, (double)arow, c2, 0, 0, 0);
    __syncthreads();

    // ---- scale to cosine logits via calibrated labels, cast fp32, reshard ----
#pragma unroll
    for (int i = 0; i < 4; ++i) {
        const int tr = (int)(c1[i] * 0.25);      // true token-within-tile label
        const int ec = (int)(c2[i] * 0.25);      // true expert-within-16 label
        const int e  = etile * 16 + ec;
        logits[tr][e] = (float)(acc[i] * xinv_lds[tr] * pinv_lds[e]);
    }
    __syncthreads();

    // ---- epilogue: np fp32 softmax bit-chain + rank by (w32 desc, idx asc) ----
#pragma unroll 1
    for (int i = 0; i < 4; ++i) {
        const int tl = w * 4 + i;
        const float l32 = logits[tl][lane];

        float m = l32;
#pragma unroll
        for (int d = 1; d < 64; d <<= 1) {
            float o = __shfl_xor(m, d, 64);
            m = fmaxf(m, o);
        }
        const float dd = l32 - m;
        const float e32 = (float)exp((double)dd);

        // numpy pairwise_sum (n=64): 8 accumulators over stride 8
        float r[8];
#pragma unroll
        for (int j = 0; j < 8; ++j) {
            float rj = __shfl(e32, j, 64);
#pragma unroll
            for (int b = 1; b < 8; ++b)
                rj += __shfl(e32, j + 8 * b, 64);
            r[j] = rj;
        }
        const float S = ((r[0] + r[1]) + (r[2] + r[3])) +
                        ((r[4] + r[5]) + (r[6] + r[7]));
        const float wgt = e32 / S;

        int rank = 0;
#pragma unroll 1
        for (int sdist = 1; sdist < 64; ++sdist) {
            float ow = __shfl_xor(wgt, sdist, 64);
            int j = lane ^ sdist;
            rank += (ow > wgt) || (ow == wgt && j < lane);
        }

        if (rank < TOPK) {
            const int tok = tok0 + tl;
            out[tok * TOPK + rank] = wgt;                       // routing_weights
            out[NTOK * TOPK + tok * TOPK + rank] = (float)lane; // selected_experts
        }
    }
}

extern "C" void kernel_launch(void* const* d_in, const int* in_sizes, int n_in,
                              void* d_out, int out_size, void* d_ws, size_t ws_size,
                              hipStream_t stream) {
    const float* x     = (const float*)d_in[0];
    const float* proto = (const float*)d_in[1];
    float* out         = (float*)d_out;
    (void)d_ws; (void)ws_size; (void)in_sizes; (void)n_in; (void)out_size;

    router_kernel<<<NTOK / TB, 256, 0, stream>>>(x, proto, out);
}

// Round 11
// 153.264 us; speedup vs baseline: 2.4470x; 1.5158x over previous
//
#include <hip/hip_runtime.h>
#include <math.h>

#define NTOK   16384
#define DIM    2048
#define NEXP   64
#define TOPK   8
#define TB     16          // tokens per block -> grid 1024 = 4 blocks/CU
#define KC     64          // K chunk
#define NCHUNK (DIM / KC)  // 32

typedef double v4d __attribute__((ext_vector_type(4)));

// ---- fused kernel: 4 waves x 2 k-split MFMA chains, global->reg, no spills ----
// launch_bounds(256,2): the (256,4) bound forced a 64-VGPR split and spilled
// (r9/r10, WRITE_SIZE 424-732MB). (256,2) is the known-good r8 config: VGPR<=128,
// zero spill; actual occupancy then lands at 4 waves/SIMD from usage ~100 regs.
__global__ __launch_bounds__(256, 2) void router_kernel(
    const float* __restrict__ x, const float* __restrict__ proto,
    float* __restrict__ out)
{
    __shared__ float  logits[TB][NEXP];   // 4 KiB
    __shared__ double xinv_lds[TB];
    __shared__ double pinv_lds[NEXP];

    const int tid  = threadIdx.x;
    const int lane = tid & 63;
    const int w    = tid >> 6;            // wave 0..3 = expert tile
    const int tok0 = blockIdx.x * TB;

    const int etile = w;                  // wave owns experts [16w, 16w+16)
    const int arow  = lane & 15;          // A-row / B-col label
    const int akg   = lane >> 4;          // quarter-wave k-group
    const int kbase = akg * 16;           // lane's private 16-k segment

    // 2 independent k-split chains (chain0: q=0,1 ; chain1: q=2,3)
    v4d acc0 = {0., 0., 0., 0.}, acc1 = {0., 0., 0., 0.};
    double sumsq = 0.0, psq = 0.0;

    const float* xrow = x     + (size_t)(tok0 + arow)       * DIM + kbase;
    const float* prow = proto + (size_t)(etile * 16 + arow) * DIM + kbase;

    // named operand buffers (no arrays -> compile-time indices, no scratch)
    float4 xa0, xa1, xa2, xa3, pa0, pa1, pa2, pa3;   // set A (even chunks)
    float4 xb0, xb1, xb2, xb3, pb0, pb1, pb2, pb3;   // set B (odd chunks)

#define LOADSET(A0, A1, A2, A3, B0, B1, B2, B3, c) do {             \
    const float* _xp = xrow + (c) * KC;                             \
    const float* _pp = prow + (c) * KC;                             \
    A0 = *(const float4*)(_xp);      A1 = *(const float4*)(_xp + 4);\
    A2 = *(const float4*)(_xp + 8);  A3 = *(const float4*)(_xp + 12);\
    B0 = *(const float4*)(_pp);      B1 = *(const float4*)(_pp + 4);\
    B2 = *(const float4*)(_pp + 8);  B3 = *(const float4*)(_pp + 12);\
    } while (0)

#define NORMQ(A, B) do {                                            \
    double a0 = (double)A.x, a1 = (double)A.y,                      \
           a2 = (double)A.z, a3 = (double)A.w;                      \
    double u0 = (double)B.x, u1 = (double)B.y,                      \
           u2 = (double)B.z, u3 = (double)B.w;                      \
    sumsq += a0*a0 + a1*a1 + a2*a2 + a3*a3;                         \
    psq   += u0*u0 + u1*u1 + u2*u2 + u3*u3;                         \
    } while (0)

#define MFMA2(Aq, Bq, Ar, Br, S)                                                        \
    acc0 = __builtin_amdgcn_mfma_f64_16x16x4f64((double)Aq.S, (double)Bq.S, acc0, 0, 0, 0); \
    acc1 = __builtin_amdgcn_mfma_f64_16x16x4f64((double)Ar.S, (double)Br.S, acc1, 0, 0, 0);

#define COMPUTE(A0, A1, A2, A3, B0, B1, B2, B3) do {                \
    NORMQ(A0, B0); NORMQ(A1, B1); NORMQ(A2, B2); NORMQ(A3, B3);     \
    MFMA2(A0, B0, A2, B2, x)                                        \
    MFMA2(A0, B0, A2, B2, y)                                        \
    MFMA2(A0, B0, A2, B2, z)                                        \
    MFMA2(A0, B0, A2, B2, w)                                        \
    MFMA2(A1, B1, A3, B3, x)                                        \
    MFMA2(A1, B1, A3, B3, y)                                        \
    MFMA2(A1, B1, A3, B3, z)                                        \
    MFMA2(A1, B1, A3, B3, w)                                        \
    } while (0)

    // ---- barrier-free main loop, unroll-by-2, named double buffers ----
    LOADSET(xa0, xa1, xa2, xa3, pa0, pa1, pa2, pa3, 0);
    for (int c = 0; c < NCHUNK; c += 2) {
        LOADSET(xb0, xb1, xb2, xb3, pb0, pb1, pb2, pb3, c + 1);
        COMPUTE(xa0, xa1, xa2, xa3, pa0, pa1, pa2, pa3);
        if (c + 2 < NCHUNK)
            LOADSET(xa0, xa1, xa2, xa3, pa0, pa1, pa2, pa3, c + 2);
        COMPUTE(xb0, xb1, xb2, xb3, pb0, pb1, pb2, pb3);
    }

    // ---- combine k-split chains (f64; ~1e-16 rel order change, flip-safe) ----
    const v4d acc = acc0 + acc1;

    // ---- norms: butterfly over the 4 k-quarters (r8/r9/r10 pattern) ----
    sumsq += __shfl_xor(sumsq, 16, 64);
    sumsq += __shfl_xor(sumsq, 32, 64);
    psq   += __shfl_xor(psq, 16, 64);
    psq   += __shfl_xor(psq, 32, 64);
    if (akg == 0) {   // duplicate waves write identical xinv bits -> benign
        xinv_lds[arow]              = 1.0 / fmax(sqrt(sumsq), 1e-12);
        pinv_lds[etile * 16 + arow] = 1.0 / fmax(sqrt(psq), 1e-12);
    }

    // ---- layout calibration (verified r4), AFTER loop to shrink live range ----
    v4d c1 = {0., 0., 0., 0.}, c2 = {0., 0., 0., 0.};
    c1 = __builtin_amdgcn_mfma_f64_16x16x4f64((double)arow, 1.0, c1, 0, 0, 0);
    c2 = __builtin_amdgcn_mfma_f64_16x16x4f64(1.0, (double)arow, c2, 0, 0, 0);
    __syncthreads();

    // ---- scale to cosine logits via calibrated labels, cast fp32, reshard ----
#pragma unroll
    for (int i = 0; i < 4; ++i) {
        const int tr = (int)(c1[i] * 0.25);      // true token-within-tile label
        const int ec = (int)(c2[i] * 0.25);      // true expert-within-16 label
        const int e  = etile * 16 + ec;
        logits[tr][e] = (float)(acc[i] * xinv_lds[tr] * pinv_lds[e]);
    }
    __syncthreads();

    // ---- epilogue: np fp32 softmax bit-chain + rank by (w32 desc, idx asc) ----
#pragma unroll 1
    for (int i = 0; i < 4; ++i) {
        const int tl = w * 4 + i;
        const float l32 = logits[tl][lane];

        float m = l32;
#pragma unroll
        for (int d = 1; d < 64; d <<= 1) {
            float o = __shfl_xor(m, d, 64);
            m = fmaxf(m, o);
        }
        const float dd = l32 - m;
        const float e32 = (float)exp((double)dd);

        // numpy pairwise_sum (n=64): 8 accumulators over stride 8
        float r[8];
#pragma unroll
        for (int j = 0; j < 8; ++j) {
            float rj = __shfl(e32, j, 64);
#pragma unroll
            for (int b = 1; b < 8; ++b)
                rj += __shfl(e32, j + 8 * b, 64);
            r[j] = rj;
        }
        const float S = ((r[0] + r[1]) + (r[2] + r[3])) +
                        ((r[4] + r[5]) + (r[6] + r[7]));
        const float wgt = e32 / S;

        int rank = 0;
#pragma unroll 1
        for (int sdist = 1; sdist < 64; ++sdist) {
            float ow = __shfl_xor(wgt, sdist, 64);
            int j = lane ^ sdist;
            rank += (ow > wgt) || (ow == wgt && j < lane);
        }

        if (rank < TOPK) {
            const int tok = tok0 + tl;
            out[tok * TOPK + rank] = wgt;                       // routing_weights
            out[NTOK * TOPK + tok * TOPK + rank] = (float)lane; // selected_experts
        }
    }
}

extern "C" void kernel_launch(void* const* d_in, const int* in_sizes, int n_in,
                              void* d_out, int out_size, void* d_ws, size_t ws_size,
                              hipStream_t stream) {
    const float* x     = (const float*)d_in[0];
    const float* proto = (const float*)d_in[1];
    float* out         = (float*)d_out;
    (void)d_ws; (void)ws_size; (void)in_sizes; (void)n_in; (void)out_size;

    router_kernel<<<NTOK / TB, 256, 0, stream>>>(x, proto, out);
}

// Round 12
// 146.107 us; speedup vs baseline: 2.5668x; 1.0490x over previous
//
#include <hip/hip_runtime.h>
#include <math.h>

#define NTOK   16384
#define DIM    2048
#define NEXP   64
#define TOPK   8
#define TB     16          // tokens per block -> grid 1024
#define KC     32          // K chunk (halved: shrinks operand buffers to fit 4 waves/SIMD)
#define NCHUNK (DIM / KC)  // 64

typedef double v4d __attribute__((ext_vector_type(4)));

// ---- fused kernel: 4 waves x 4 k-split MFMA chains, ~105 VGPR, no spills ----
// (256,2): r9/r10 showed (256,4) force-caps at 64 VGPR and spills to scratch.
__global__ __launch_bounds__(256, 2) void router_kernel(
    const float* __restrict__ x, const float* __restrict__ proto,
    float* __restrict__ out)
{
    __shared__ float  logits[TB][NEXP];   // 4 KiB
    __shared__ double xinv_lds[TB];
    __shared__ double pinv_lds[NEXP];

    const int tid  = threadIdx.x;
    const int lane = tid & 63;
    const int w    = tid >> 6;            // wave 0..3 = expert tile
    const int tok0 = blockIdx.x * TB;

    const int etile = w;                  // wave owns experts [16w, 16w+16)
    const int arow  = lane & 15;          // A-row / B-col label
    const int akg   = lane >> 4;          // quarter-wave k-group
    const int kbase = akg * 8;            // lane's private 8-k segment per chunk

    // 4 independent k-split chains (chain j = float4 component j)
    v4d acc0 = {0., 0., 0., 0.}, acc1 = {0., 0., 0., 0.};
    v4d acc2 = {0., 0., 0., 0.}, acc3 = {0., 0., 0., 0.};
    double sumsq = 0.0, psq = 0.0;

    const float* xrow = x     + (size_t)(tok0 + arow)       * DIM + kbase;
    const float* prow = proto + (size_t)(etile * 16 + arow) * DIM + kbase;

    // named operand buffers: 8 float4 = 32 VGPR total
    float4 xa0, xa1, pa0, pa1;   // set A (even chunks)
    float4 xb0, xb1, pb0, pb1;   // set B (odd chunks)

#define LOADSET(X0, X1, P0, P1, c) do {                             \
    const float* _xp = xrow + (c) * KC;                             \
    const float* _pp = prow + (c) * KC;                             \
    X0 = *(const float4*)(_xp);  X1 = *(const float4*)(_xp + 4);    \
    P0 = *(const float4*)(_pp);  P1 = *(const float4*)(_pp + 4);    \
    } while (0)

#define NORMQ(A, B) do {                                            \
    double a0 = (double)A.x, a1 = (double)A.y,                      \
           a2 = (double)A.z, a3 = (double)A.w;                      \
    double u0 = (double)B.x, u1 = (double)B.y,                      \
           u2 = (double)B.z, u3 = (double)B.w;                      \
    sumsq += a0*a0 + a1*a1 + a2*a2 + a3*a3;                         \
    psq   += u0*u0 + u1*u1 + u2*u2 + u3*u3;                         \
    } while (0)

// chain j <- component j; two k-halves h=0,1 per chunk
#define COMPUTE(X0, X1, P0, P1) do {                                \
    NORMQ(X0, P0); NORMQ(X1, P1);                                   \
    acc0 = __builtin_amdgcn_mfma_f64_16x16x4f64((double)X0.x, (double)P0.x, acc0, 0, 0, 0); \
    acc1 = __builtin_amdgcn_mfma_f64_16x16x4f64((double)X0.y, (double)P0.y, acc1, 0, 0, 0); \
    acc2 = __builtin_amdgcn_mfma_f64_16x16x4f64((double)X0.z, (double)P0.z, acc2, 0, 0, 0); \
    acc3 = __builtin_amdgcn_mfma_f64_16x16x4f64((double)X0.w, (double)P0.w, acc3, 0, 0, 0); \
    acc0 = __builtin_amdgcn_mfma_f64_16x16x4f64((double)X1.x, (double)P1.x, acc0, 0, 0, 0); \
    acc1 = __builtin_amdgcn_mfma_f64_16x16x4f64((double)X1.y, (double)P1.y, acc1, 0, 0, 0); \
    acc2 = __builtin_amdgcn_mfma_f64_16x16x4f64((double)X1.z, (double)P1.z, acc2, 0, 0, 0); \
    acc3 = __builtin_amdgcn_mfma_f64_16x16x4f64((double)X1.w, (double)P1.w, acc3, 0, 0, 0); \
    } while (0)

    // ---- barrier-free main loop, unroll-by-2, named double buffers ----
    LOADSET(xa0, xa1, pa0, pa1, 0);
    for (int c = 0; c < NCHUNK; c += 2) {
        LOADSET(xb0, xb1, pb0, pb1, c + 1);
        COMPUTE(xa0, xa1, pa0, pa1);
        if (c + 2 < NCHUNK)
            LOADSET(xa0, xa1, pa0, pa1, c + 2);
        COMPUTE(xb0, xb1, pb0, pb1);
    }

    // ---- combine k-split chains (r9/r10-validated form) ----
    const v4d acc = (acc0 + acc1) + (acc2 + acc3);

    // ---- norms: butterfly over the 4 k-quarters ----
    sumsq += __shfl_xor(sumsq, 16, 64);
    sumsq += __shfl_xor(sumsq, 32, 64);
    psq   += __shfl_xor(psq, 16, 64);
    psq   += __shfl_xor(psq, 32, 64);
    if (akg == 0) {   // duplicate waves write identical xinv bits -> benign
        xinv_lds[arow]              = 1.0 / fmax(sqrt(sumsq), 1e-12);
        pinv_lds[etile * 16 + arow] = 1.0 / fmax(sqrt(psq), 1e-12);
    }

    // ---- layout calibration (verified r4), after loop to shrink live range ----
    v4d c1 = {0., 0., 0., 0.}, c2 = {0., 0., 0., 0.};
    c1 = __builtin_amdgcn_mfma_f64_16x16x4f64((double)arow, 1.0, c1, 0, 0, 0);
    c2 = __builtin_amdgcn_mfma_f64_16x16x4f64(1.0, (double)arow, c2, 0, 0, 0);
    __syncthreads();

    // ---- scale to cosine logits via calibrated labels, cast fp32, reshard ----
#pragma unroll
    for (int i = 0; i < 4; ++i) {
        const int tr = (int)(c1[i] * 0.25);      // true token-within-tile label
        const int ec = (int)(c2[i] * 0.25);      // true expert-within-16 label
        const int e  = etile * 16 + ec;
        logits[tr][e] = (float)(acc[i] * xinv_lds[tr] * pinv_lds[e]);
    }
    __syncthreads();

    // ---- epilogue: np fp32 softmax bit-chain + rank by (w32 desc, idx asc) ----
#pragma unroll 1
    for (int i = 0; i < 4; ++i) {
        const int tl = w * 4 + i;
        const float l32 = logits[tl][lane];

        float m = l32;
#pragma unroll
        for (int d = 1; d < 64; d <<= 1) {
            float o = __shfl_xor(m, d, 64);
            m = fmaxf(m, o);
        }
        const float dd = l32 - m;
        const float e32 = (float)exp((double)dd);

        // numpy pairwise_sum (n=64): 8 accumulators over stride 8
        float r[8];
#pragma unroll
        for (int j = 0; j < 8; ++j) {
            float rj = __shfl(e32, j, 64);
#pragma unroll
            for (int b = 1; b < 8; ++b)
                rj += __shfl(e32, j + 8 * b, 64);
            r[j] = rj;
        }
        const float S = ((r[0] + r[1]) + (r[2] + r[3])) +
                        ((r[4] + r[5]) + (r[6] + r[7]));
        const float wgt = e32 / S;

        int rank = 0;
#pragma unroll 1
        for (int sdist = 1; sdist < 64; ++sdist) {
            float ow = __shfl_xor(wgt, sdist, 64);
            int j = lane ^ sdist;
            rank += (ow > wgt) || (ow == wgt && j < lane);
        }

        if (rank < TOPK) {
            const int tok = tok0 + tl;
            out[tok * TOPK + rank] = wgt;                       // routing_weights
            out[NTOK * TOPK + tok * TOPK + rank] = (float)lane; // selected_experts
        }
    }
}

extern "C" void kernel_launch(void* const* d_in, const int* in_sizes, int n_in,
                              void* d_out, int out_size, void* d_ws, size_t ws_size,
                              hipStream_t stream) {
    const float* x     = (const float*)d_in[0];
    const float* proto = (const float*)d_in[1];
    float* out         = (float*)d_out;
    (void)d_ws; (void)ws_size; (void)in_sizes; (void)n_in; (void)out_size;

    router_kernel<<<NTOK / TB, 256, 0, stream>>>(x, proto, out);
}